// Round 10
// baseline (6682.530 us; speedup 1.0000x reference)
//
#include <hip/hip_runtime.h>
#include <hip/hip_bf16.h>

#define DIM 896
#define TT 4096
#define BB 8
#define NS 64           // slots
#define CC 128          // sequential chunk length
#define NC 32           // TT/CC
#define RCH 256         // replay chunk length (k2)
#define NRC 16          // TT/RCH
#define NSLICE 14       // dim slices in kB

typedef float floatx4 __attribute__((ext_vector_type(4)));
typedef short short8 __attribute__((ext_vector_type(8)));

// -------- DPP wave64 reductions (VALU, no DS pipe) --------
#define DPP_F(x_, ctrl_, rmask_, old_) \
  __int_as_float(__builtin_amdgcn_update_dpp(__float_as_int(old_), __float_as_int(x_), (ctrl_), (rmask_), 0xf, false))

__device__ __forceinline__ float wave_sum64(float x) {
    x += DPP_F(x, 0x111, 0xf, 0.0f);   // row_shr:1
    x += DPP_F(x, 0x112, 0xf, 0.0f);   // row_shr:2
    x += DPP_F(x, 0x114, 0xf, 0.0f);   // row_shr:4
    x += DPP_F(x, 0x118, 0xf, 0.0f);   // row_shr:8
    x += DPP_F(x, 0x142, 0xa, 0.0f);   // row_bcast:15 -> rows 1,3
    x += DPP_F(x, 0x143, 0xc, 0.0f);   // row_bcast:31 -> rows 2,3
    return __int_as_float(__builtin_amdgcn_readlane(__float_as_int(x), 63));
}
__device__ __forceinline__ float wave_max64(float x) {
    x = fmaxf(x, DPP_F(x, 0x111, 0xf, -INFINITY));
    x = fmaxf(x, DPP_F(x, 0x112, 0xf, -INFINITY));
    x = fmaxf(x, DPP_F(x, 0x114, 0xf, -INFINITY));
    x = fmaxf(x, DPP_F(x, 0x118, 0xf, -INFINITY));
    x = fmaxf(x, DPP_F(x, 0x142, 0xa, -INFINITY));
    x = fmaxf(x, DPP_F(x, 0x143, 0xc, -INFINITY));
    return __int_as_float(__builtin_amdgcn_readlane(__float_as_int(x), 63));
}

__device__ __forceinline__ float rfl_f(float x) {
    return __int_as_float(__builtin_amdgcn_readfirstlane(__float_as_int(x)));
}
__device__ __forceinline__ float rl_f(float x, int l) {
    return __int_as_float(__builtin_amdgcn_readlane(__float_as_int(x), l));
}

// ---------------- K0: per-token dots  R = h.Wnm1, P2 = h.Wnm2, Q = h.Wwg1 ----------------
__global__ __launch_bounds__(64) void k0_dots(const float* __restrict__ h,
                                              const float* __restrict__ W_nm,
                                              const float* __restrict__ W_wg,
                                              float* __restrict__ R, float* __restrict__ Q,
                                              float* __restrict__ P2) {
    const int r = blockIdx.x;
    const int lane = threadIdx.x;
    const float2* hr = (const float2*)(h + (size_t)r * DIM);
    const float2* w0 = (const float2*)W_nm;
    const float2* w1 = (const float2*)(W_nm + DIM);
    const float2* w2 = (const float2*)W_wg;
    float a = 0.f, bsum = 0.f, c = 0.f;
    #pragma unroll
    for (int i = 0; i < 7; ++i) {
        int idx = lane + 64 * i;
        float2 hv = hr[idx];
        float2 a0 = w0[idx], a1 = w1[idx], a2 = w2[idx];
        a = fmaf(hv.x, a0.x, fmaf(hv.y, a0.y, a));
        bsum = fmaf(hv.x, a1.x, fmaf(hv.y, a1.y, bsum));
        c = fmaf(hv.x, a2.x, fmaf(hv.y, a2.y, c));
    }
    #pragma unroll
    for (int off = 32; off; off >>= 1) {
        a += __shfl_xor(a, off);
        bsum += __shfl_xor(bsum, off);
        c += __shfl_xor(c, off);
    }
    if (lane == 0) { R[r] = a; P2[r] = bsum; Q[r] = c; }
}

// ---------------- KG: per-chunk Gram diagonal blocks  G[tau][t'] = h_tau . h_t' ----------
__global__ __launch_bounds__(256) void kG_gram(const float* __restrict__ h,
                                               float* __restrict__ Gd) {
    const int blk = blockIdx.x;           // (b*NC + c)*2 + half
    const int bc = blk >> 1, half = blk & 1;
    const int b = bc / NC, c = bc % NC;
    const int tid = threadIdx.x;
    const int ti = tid >> 4, tj = tid & 15;
    __shared__ float Hs[32][132];
    float acc[8][4];
    #pragma unroll
    for (int u = 0; u < 8; u++)
        #pragma unroll
        for (int v = 0; v < 4; v++) acc[u][v] = 0.f;
    const size_t hb = (size_t)b * TT * DIM + (size_t)c * CC * DIM;
    for (int kb = 0; kb < 28; ++kb) {
        __syncthreads();
        #pragma unroll
        for (int l = 0; l < 4; ++l) {
            int idx = tid + l * 256;
            int r = idx >> 3, kq = idx & 7;
            float4 f = *(const float4*)&h[hb + (size_t)r * DIM + kb * 32 + kq * 4];
            Hs[kq * 4 + 0][r] = f.x; Hs[kq * 4 + 1][r] = f.y;
            Hs[kq * 4 + 2][r] = f.z; Hs[kq * 4 + 3][r] = f.w;
        }
        __syncthreads();
        #pragma unroll 4
        for (int k = 0; k < 32; ++k) {
            float4 a0 = *(const float4*)&Hs[k][ti * 8];
            float4 a1 = *(const float4*)&Hs[k][ti * 8 + 4];
            float4 bv = *(const float4*)&Hs[k][half * 64 + tj * 4];
            float av[8] = {a0.x, a0.y, a0.z, a0.w, a1.x, a1.y, a1.z, a1.w};
            float bb[4] = {bv.x, bv.y, bv.z, bv.w};
            #pragma unroll
            for (int u = 0; u < 8; u++)
                #pragma unroll
                for (int v = 0; v < 4; v++)
                    acc[u][v] = fmaf(av[u], bb[v], acc[u][v]);
        }
    }
    float* gp = Gd + (size_t)bc * CC * CC;
    #pragma unroll
    for (int u = 0; u < 8; u++) {
        float4 o = {acc[u][0], acc[u][1], acc[u][2], acc[u][3]};
        *(float4*)&gp[(size_t)(ti * 8 + u) * CC + half * 64 + tj * 4] = o;
    }
}

// ---------------- KB: fused mem-replay (chunk c-1) + Base partials for chunk c -----------
#define MC_(i) case i: mc[i] = fmaf(mc[i], om, wh); break;
__global__ __launch_bounds__(256) void kB_base(const float* __restrict__ h,
                                               const float* __restrict__ wgbuf,
                                               const int* __restrict__ ssbuf,
                                               float* __restrict__ memS,
                                               float* __restrict__ snap,
                                               float* __restrict__ Bpart,
                                               int c) {
    const int slice = blockIdx.x;
    const int b = blockIdx.y;
    const int tid = threadIdx.x;
    __shared__ float wsh[CC];
    __shared__ int   ssh[CC];
    __shared__ float Asb[64][65];     // [k within slice][s]
    __shared__ float Bsb[CC][65];     // [t'][k]

    if (tid < CC) {
        wsh[tid] = wgbuf[b * TT + (c - 1) * CC + tid];
        ssh[tid] = ssbuf[b * TT + (c - 1) * CC + tid];
    }
    const int q = tid >> 6, d = tid & 63;
    const int dg = slice * 64 + d;
    float mc[16];
    #pragma unroll
    for (int j = 0; j < 16; j++) mc[j] = memS[((size_t)b * NS + q * 16 + j) * DIM + dg];
    __syncthreads();

    const size_t hb = (size_t)b * TT * DIM + (size_t)((c - 1) * CC) * DIM + dg;
    float hv[16];
    #pragma unroll
    for (int j = 0; j < 16; ++j) hv[j] = h[hb + (size_t)j * DIM];
    for (int i0 = 0; i0 < CC; i0 += 16) {
        float hvn[16];
        if (i0 + 16 < CC) {
            #pragma unroll
            for (int j = 0; j < 16; ++j) hvn[j] = h[hb + (size_t)(i0 + 16 + j) * DIM];
        }
        #pragma unroll
        for (int j = 0; j < 16; ++j) {
            const int i = i0 + j;
            float hvv = hv[j];
            int ss = __builtin_amdgcn_readfirstlane(ssh[i]);   // block-uniform -> scalar switch
            float w = rfl_f(wsh[i]);
            if ((ss >> 4) == q) {
                float om = 1.f - w, wh = w * hvv;
                switch (ss & 15) {
                    MC_(0) MC_(1) MC_(2) MC_(3) MC_(4) MC_(5) MC_(6) MC_(7)
                    MC_(8) MC_(9) MC_(10) MC_(11) MC_(12) MC_(13) MC_(14) MC_(15)
                }
            }
        }
        #pragma unroll
        for (int j = 0; j < 16; ++j) hv[j] = hvn[j];
    }
    #pragma unroll
    for (int j = 0; j < 16; j++) {
        memS[((size_t)b * NS + q * 16 + j) * DIM + dg] = mc[j];
        Asb[d][q * 16 + j] = mc[j];
    }
    if ((c & 1) == 0) {
        const int r = c >> 1;
        #pragma unroll
        for (int j = 0; j < 16; j++)
            snap[(((size_t)b * NRC + r) * NS + q * 16 + j) * DIM + dg] = mc[j];
    }
    const size_t hb2 = (size_t)b * TT * DIM + (size_t)(c * CC) * DIM + slice * 64;
    for (int idx = tid; idx < CC * 64; idx += 256) {
        int tp = idx >> 6, k = idx & 63;
        Bsb[tp][k] = h[hb2 + (size_t)tp * DIM + k];
    }
    __syncthreads();

    const int tg = tid >> 3, sg = tid & 7;
    float acc[4][8];
    #pragma unroll
    for (int v = 0; v < 4; v++)
        #pragma unroll
        for (int u = 0; u < 8; u++) acc[v][u] = 0.f;
    #pragma unroll 4
    for (int k = 0; k < 64; ++k) {
        float bv[4], av[8];
        #pragma unroll
        for (int v = 0; v < 4; v++) bv[v] = Bsb[tg * 4 + v][k];
        #pragma unroll
        for (int u = 0; u < 8; u++) av[u] = Asb[k][sg * 8 + u];
        #pragma unroll
        for (int v = 0; v < 4; v++)
            #pragma unroll
            for (int u = 0; u < 8; u++)
                acc[v][u] = fmaf(bv[v], av[u], acc[v][u]);
    }
    float* bp = Bpart + ((size_t)(slice * BB + b)) * CC * NS;
    #pragma unroll
    for (int v = 0; v < 4; v++) {
        float4 o0 = {acc[v][0], acc[v][1], acc[v][2], acc[v][3]};
        float4 o1 = {acc[v][4], acc[v][5], acc[v][6], acc[v][7]};
        *(float4*)&bp[(size_t)(tg * 4 + v) * NS + sg * 8] = o0;
        *(float4*)&bp[(size_t)(tg * 4 + v) * NS + sg * 8 + 4] = o1;
    }
}

// ---------------- KS v5: LDS-staged Gd + branchless step body ----------------------------
#define SIDX(r, c_) (((r) << 6) + (((c_) ^ ((r) & 63))))
__global__ __launch_bounds__(256) void kS_seq(const float* __restrict__ Bpart,
                                              const float* __restrict__ Gd,
                                              const float* __restrict__ Rv,
                                              const float* __restrict__ Qv,
                                              const float* __restrict__ P2v,
                                              const int* __restrict__ mask,
                                              const float* __restrict__ b_nm,
                                              const float* __restrict__ b_wg,
                                              const float* __restrict__ W_wg,
                                              float* __restrict__ Kvec,
                                              float* __restrict__ fbuf,
                                              float* __restrict__ wgbuf,
                                              int* __restrict__ ssbuf,
                                              int c) {
    const int b = blockIdx.x;
    const int tid = threadIdx.x;
    const int lane = tid & 63;
    const int wv = tid >> 6;
    __shared__ float S[129 * 64];        // swizzled; row 128 = dummy sink
    __shared__ float Gb[2][17 * 128];    // 16-row bands + dummy row 16
    const int tb = b * TT + c * CC;
    const float* gdc = Gd + (size_t)(b * NC + c) * CC * CC;

    // ---- stage S (14-way Bpart reduce), all 4 waves ----
    if (c == 0) {
        for (int t = wv * 32; t < wv * 32 + 32; ++t) S[SIDX(t, lane)] = 0.f;
    } else {
        const float* bp0 = Bpart + (size_t)b * CC * NS;
        for (int t = wv * 32; t < wv * 32 + 32; ++t) {
            float s = 0.f;
            #pragma unroll
            for (int sl = 0; sl < NSLICE; ++sl)
                s += bp0[(size_t)sl * (BB * CC * NS) + (size_t)t * NS + lane];
            S[SIDX(t, lane)] = s;
        }
    }
    // ---- stage Gd band 0 (rows 0..15), all 4 waves ----
    for (int idx = tid; idx < 512; idx += 256) {
        int r = idx >> 5, cq = idx & 31;
        *(float4*)&Gb[0][r * 128 + cq * 4] = *(const float4*)&gdc[(size_t)r * CC + cq * 4];
    }

    // ---- wave0-only register state ----
    float cur = 0.f, p1 = 0.f, p2 = 0.f, p3 = 0.f, K = 0.f;
    float Rl0 = 0.f, Rl1 = 0.f, Ql0 = 0.f, Ql1 = 0.f;
    float Pl0 = 0.f, Pl1 = 0.f, Ml0 = 0.f, Ml1 = 0.f;
    float bnm = 0.f, bwg = 0.f, wD = 0.f;
    const float scale = 1.0f / sqrtf((float)DIM);
    if (wv == 0) {
        cur = S[SIDX(0, lane)];
        p1  = S[SIDX(1, lane)];
        p2  = S[SIDX(2, lane)];
        p3  = S[SIDX(3, lane)];
        K = Kvec[b * NS + lane];
        Rl0 = Rv[tb + lane];  Rl1 = Rv[tb + 64 + lane];
        Ql0 = Qv[tb + lane];  Ql1 = Qv[tb + 64 + lane];
        Pl0 = P2v[tb + lane]; Pl1 = P2v[tb + 64 + lane];
        Ml0 = (float)mask[tb + lane]; Ml1 = (float)mask[tb + 64 + lane];
        bnm = b_nm[0]; bwg = b_wg[0]; wD = W_wg[DIM];
    }
    __syncthreads();

    for (int bb = 0; bb < 8; ++bb) {
        if (wv == 0) {
            const int base = bb * 16;
            const float* gcur = Gb[bb & 1];
            const float Rb = (base & 64) ? Rl1 : Rl0;
            const float Qb = (base & 64) ? Ql1 : Ql0;
            const float Pb = (base & 64) ? Pl1 : Pl0;
            const float Mb = (base & 64) ? Ml1 : Ml0;
            float g0 = gcur[(base + 1 + lane) & 127];
            float g1 = gcur[(base + 65 + lane) & 127];
            #pragma unroll 4
            for (int s = 0; s < 16; ++s) {
                const int tau = base + s;
                float g0n = gcur[(s + 1) * 128 + ((tau + 2 + lane) & 127)];
                float g1n = gcur[(s + 1) * 128 + ((tau + 66 + lane) & 127)];
                int rp4 = tau + 4; rp4 = (rp4 > 128) ? 128 : rp4;
                float p4 = S[SIDX(rp4, lane)];
                const float Rt = rl_f(Rb, tau & 63);
                const float Qt = rl_f(Qb, tau & 63);
                const float Pt = rl_f(Pb, tau & 63);
                const float Mk = rl_f(Mb, tau & 63);

                float sco = cur * scale;
                float mv = wave_max64(sco);
                float e = __expf(sco);
                float se = wave_sum64(e);
                float sk = wave_sum64(e * K);
                unsigned long long bal = __ballot(sco == mv);
                int mi = (int)__ffsll(bal) - 1;             // lowest-index tie-break

                float inv = 1.f / se;
                fbuf[((size_t)tb + tau) * NS + lane] = e * inv;
                float gdot = sk * inv;
                float g = 1.f / (1.f + __expf(-(Rt + gdot + bnm)));
                float w = 1.f / (1.f + __expf(-(Qt + g * wD + bwg)));
                w = fminf(w, 0.2f) * Mk;
                if (lane == 0) {
                    wgbuf[tb + tau] = w;
                    ssbuf[tb + tau] = mi;
                }
                float om = 1.f - w;
                K = (lane == mi) ? fmaf(K, om, w * Pt) : K;

                int r1 = tau + 1 + lane;
                int ix1 = (lane >= 4 && r1 < 128) ? SIDX(r1, mi) : (128 * 64 + lane);
                int r2 = tau + 65 + lane;
                int ix2 = (r2 < 128) ? SIDX(r2, mi) : (128 * 64 + lane);
                S[ix1] = fmaf(S[ix1], om, w * g0);
                S[ix2] = fmaf(S[ix2], om, w * g1);

                const float q1 = rl_f(g0, 0), q2 = rl_f(g0, 1);
                const float q3 = rl_f(g0, 2), q4 = rl_f(g0, 3);
                const bool m_ = (lane == mi);
                p1 = m_ ? fmaf(p1, om, w * q1) : p1;
                p2 = m_ ? fmaf(p2, om, w * q2) : p2;
                p3 = m_ ? fmaf(p3, om, w * q3) : p3;
                p4 = m_ ? fmaf(p4, om, w * q4) : p4;
                cur = p1; p1 = p2; p2 = p3; p3 = p4;
                g0 = g0n; g1 = g1n;
            }
        } else if (bb < 7) {
            const int bs = (bb + 1) * 16;
            float* dst = Gb[(bb + 1) & 1];
            for (int idx = tid - 64; idx < 512; idx += 192) {
                int r = idx >> 5, cq = idx & 31;
                *(float4*)&dst[r * 128 + cq * 4] =
                    *(const float4*)&gdc[(size_t)(bs + r) * CC + cq * 4];
            }
        }
        __syncthreads();
    }
    if (wv == 0) Kvec[b * NS + lane] = K;
}

// ---------------- K1: convert W_out to bf16 once ----------------
__global__ __launch_bounds__(256) void k1_wcvt(const float* __restrict__ W,
                                               __hip_bfloat16* __restrict__ Wb) {
    const int idx = blockIdx.x * 256 + threadIdx.x;     // 0..200703 float4s
    const float4 f = ((const float4*)W)[idx];
    alignas(8) __hip_bfloat16 t[4];
    t[0] = __float2bfloat16(f.x); t[1] = __float2bfloat16(f.y);
    t[2] = __float2bfloat16(f.z); t[3] = __float2bfloat16(f.w);
    *(uint2*)&Wb[(size_t)idx * 4] = *(const uint2*)t;
}

// ---------------- K2 v3: group-corrected replay -> m_t (bf16) ----------------------------
// Rank-1 exactness: within a group of 8 tokens, each step changes ONE slot by delta_j.
// Base dots vs group-start mem (512 independent FMAs, pipelined) + exact serial
// corrections m_t = base_t + sum_{j<t} f_t[ss_j]*delta_j. Breaks the compiler's
// forced step-serialization (R9 measured: per-block latency-bound, 212us at ANY grid).
#define CS_(i) case i: { float ov = mem[i]; float nv = fmaf(ov, sA, aB); mem[i] = nv; dj = nv - ov; } break;
__global__ __launch_bounds__(448) void k2_replay(const float* __restrict__ h,
                                                 const float* __restrict__ fbuf,
                                                 const float* __restrict__ wgbuf,
                                                 const int* __restrict__ ssbuf,
                                                 const float* __restrict__ snap,
                                                 __hip_bfloat16* __restrict__ Mbuf) {
    const int blk = blockIdx.x;          // 0..255 : ((b*16 + c)*2 + halfD)
    const int b = blk >> 5;
    const int c = (blk >> 1) & 15;
    const int halfD = blk & 1;
    const int tid = threadIdx.x;         // 0..447
    const int dg = halfD * 448 + tid;    // dim index

    __shared__ float lf[128 * NS];
    __shared__ float lwg[RCH];
    __shared__ int   lss[RCH];

    float mem[64];
    const float* sp = snap + (((size_t)b * NRC + c) * NS) * DIM + dg;
    #pragma unroll
    for (int s2 = 0; s2 < 64; s2++) mem[s2] = sp[(size_t)s2 * DIM];

    const int t0 = c * RCH;
    if (tid < RCH) {
        lwg[tid] = wgbuf[b * TT + t0 + tid];
        lss[tid] = ssbuf[b * TT + t0 + tid];
    }
    const size_t hbase = (size_t)b * TT * DIM + (size_t)t0 * DIM + dg;
    const size_t fbase = ((size_t)b * TT + t0) * NS;
    const size_t mrow = ((size_t)b * TT + t0) * DIM + dg;

    for (int half = 0; half < 2; ++half) {
        __syncthreads();
        const float4* src = (const float4*)(fbuf + fbase + (size_t)half * 128 * NS);
        for (int idx = tid; idx < 128 * NS / 4; idx += 448)
            ((float4*)lf)[idx] = src[idx];
        __syncthreads();

        float hv[8];
        #pragma unroll
        for (int j = 0; j < 8; ++j)
            hv[j] = h[hbase + (size_t)(half * 128 + j) * DIM];

        for (int tg = 0; tg < 128; tg += 8) {
            float hvn[8];
            if (tg + 8 < 128) {
                #pragma unroll
                for (int j = 0; j < 8; ++j)
                    hvn[j] = h[hbase + (size_t)(half * 128 + tg + 8 + j) * DIM];
            }
            // ---- base dots for the 8-token group vs group-start mem (pipelined) ----
            float bm[8];
            #pragma unroll
            for (int j = 0; j < 8; ++j) {
                const float4* f4p = (const float4*)&lf[(tg + j) * NS];
                float m0 = 0.f, m1 = 0.f, m2 = 0.f, m3 = 0.f;
                #pragma unroll
                for (int qq = 0; qq < 16; qq++) {
                    float4 f4 = f4p[qq];
                    m0 = fmaf(f4.x, mem[4 * qq], m0);
                    m1 = fmaf(f4.y, mem[4 * qq + 1], m1);
                    m2 = fmaf(f4.z, mem[4 * qq + 2], m2);
                    m3 = fmaf(f4.w, mem[4 * qq + 3], m3);
                }
                bm[j] = (m0 + m1) + (m2 + m3);
            }
            // ---- serial pass: exact rank-1 corrections + mem updates ----
            int   ssg[8];
            float dlt[8];
            #pragma unroll
            for (int j = 0; j < 8; ++j) {
                const int tt = half * 128 + tg + j;
                float m = bm[j];
                #pragma unroll
                for (int j2 = 0; j2 < 8; ++j2) {
                    if (j2 < j)
                        m = fmaf(lf[(tg + j) * NS + ssg[j2]], dlt[j2], m);
                }
                Mbuf[mrow + (size_t)tt * DIM] = __float2bfloat16(m);
                int ss = __builtin_amdgcn_readfirstlane(lss[tt]);  // block-uniform
                float w = rfl_f(lwg[tt]);
                float sA = 1.0f - w, aB = w * hv[j];
                float dj = 0.f;
                switch (ss) {
                    CS_(0) CS_(1) CS_(2) CS_(3) CS_(4) CS_(5) CS_(6) CS_(7)
                    CS_(8) CS_(9) CS_(10) CS_(11) CS_(12) CS_(13) CS_(14) CS_(15)
                    CS_(16) CS_(17) CS_(18) CS_(19) CS_(20) CS_(21) CS_(22) CS_(23)
                    CS_(24) CS_(25) CS_(26) CS_(27) CS_(28) CS_(29) CS_(30) CS_(31)
                    CS_(32) CS_(33) CS_(34) CS_(35) CS_(36) CS_(37) CS_(38) CS_(39)
                    CS_(40) CS_(41) CS_(42) CS_(43) CS_(44) CS_(45) CS_(46) CS_(47)
                    CS_(48) CS_(49) CS_(50) CS_(51) CS_(52) CS_(53) CS_(54) CS_(55)
                    CS_(56) CS_(57) CS_(58) CS_(59) CS_(60) CS_(61) CS_(62) CS_(63)
                }
                ssg[j] = ss;
                dlt[j] = dj;
            }
            #pragma unroll
            for (int j = 0; j < 8; ++j) hv[j] = hvn[j];
        }
    }
}

// ---------------- K3: row LayerNorm in place on Mbuf (bf16, bf16x2 vectorized) -----------
__global__ __launch_bounds__(64) void k3_ln(__hip_bfloat16* __restrict__ Mbuf,
                                            const float* __restrict__ ln_g,
                                            const float* __restrict__ ln_b) {
    const size_t r = blockIdx.x;
    const int lane = threadIdx.x;
    __hip_bfloat162* row2 = (__hip_bfloat162*)(Mbuf + r * DIM);
    float vx[7], vy[7];
    float s1 = 0.f, s2 = 0.f;
    #pragma unroll
    for (int i = 0; i < 7; i++) {
        __hip_bfloat162 x2 = row2[lane + 64 * i];
        float x = __bfloat162float(x2.x), y = __bfloat162float(x2.y);
        vx[i] = x; vy[i] = y;
        s1 += x + y;
        s2 = fmaf(x, x, fmaf(y, y, s2));
    }
    #pragma unroll
    for (int off = 32; off; off >>= 1) {
        s1 += __shfl_xor(s1, off);
        s2 += __shfl_xor(s2, off);
    }
    float mu = s1 * (1.0f / DIM);
    float var = fmaxf(s2 * (1.0f / DIM) - mu * mu, 0.0f);
    float rs = 1.0f / sqrtf(var + 1e-5f);
    #pragma unroll
    for (int i = 0; i < 7; i++) {
        int d = 2 * (lane + 64 * i);
        float2 lg = *(const float2*)&ln_g[d];
        float2 lb = *(const float2*)&ln_b[d];
        __hip_bfloat162 o;
        o.x = __float2bfloat16((vx[i] - mu) * rs * lg.x + lb.x);
        o.y = __float2bfloat16((vy[i] - mu) * rs * lg.y + lb.y);
        row2[lane + 64 * i] = o;
    }
}

// ---------------- K4: out = h + clip(0.5 * MN @ W_out^T) (bf16 MFMA GEMM) ----------------
__global__ __launch_bounds__(256) void k4_gemm(const __hip_bfloat16* __restrict__ Mn,
                                               const __hip_bfloat16* __restrict__ Wb,
                                               const float* __restrict__ h,
                                               float* __restrict__ out) {
    const int nt = blockIdx.x;   // 0..6
    const int mt = blockIdx.y;   // 0..255
    const int tid = threadIdx.x;
    const int wave = tid >> 6, lane = tid & 63;
    const int wr = wave >> 1, wc = wave & 1;

    __shared__ __hip_bfloat16 Asb[128 * 72];
    __shared__ __hip_bfloat16 Bsb[128 * 72];

    floatx4 acc[4][4];
    #pragma unroll
    for (int i = 0; i < 4; i++)
        #pragma unroll
        for (int jn = 0; jn < 4; jn++)
            acc[i][jn] = (floatx4){0.f, 0.f, 0.f, 0.f};

    const int lrow = lane & 15;
    const int lk = (lane >> 4) * 8;
    const int rr = tid >> 3, ch = tid & 7;

    for (int kt = 0; kt < 14; ++kt) {
        #pragma unroll
        for (int it = 0; it < 4; ++it) {
            int row = rr + 32 * it;
            const uint4* srcA = (const uint4*)(Mn + ((size_t)(mt * 128 + row)) * DIM + kt * 64 + ch * 8);
            *(uint4*)&Asb[row * 72 + ch * 8] = *srcA;
            const uint4* srcB = (const uint4*)(Wb + ((size_t)(nt * 128 + row)) * DIM + kt * 64 + ch * 8);
            *(uint4*)&Bsb[row * 72 + ch * 8] = *srcB;
        }
        __syncthreads();
        #pragma unroll
        for (int kk = 0; kk < 2; ++kk) {
            short8 af[4], bfr[4];
            #pragma unroll
            for (int i = 0; i < 4; i++)
                af[i] = *(const short8*)&Asb[(wr * 64 + i * 16 + lrow) * 72 + kk * 32 + lk];
            #pragma unroll
            for (int i2 = 0; i2 < 4; i2++)
                bfr[i2] = *(const short8*)&Bsb[(wc * 64 + i2 * 16 + lrow) * 72 + kk * 32 + lk];
            #pragma unroll
            for (int i = 0; i < 4; i++)
                #pragma unroll
                for (int jn = 0; jn < 4; jn++)
                    acc[i][jn] = __builtin_amdgcn_mfma_f32_16x16x32_bf16(af[i], bfr[jn], acc[i][jn], 0, 0, 0);
        }
        __syncthreads();
    }
    const int crow = (lane >> 4) * 4, ccol = lane & 15;
    #pragma unroll
    for (int i = 0; i < 4; i++)
        #pragma unroll
        for (int jn = 0; jn < 4; jn++)
            #pragma unroll
            for (int rg = 0; rg < 4; rg++) {
                int rG = mt * 128 + wr * 64 + i * 16 + crow + rg;
                int nG = nt * 128 + wc * 64 + jn * 16 + ccol;
                size_t idx = (size_t)rG * DIM + nG;
                float d = acc[i][jn][rg] * 0.5f;
                d = fminf(fmaxf(d, -2.0f), 2.0f);
                out[idx] = h[idx] + d;
            }
}

extern "C" void kernel_launch(void* const* d_in, const int* in_sizes, int n_in,
                              void* d_out, int out_size, void* d_ws, size_t ws_size,
                              hipStream_t stream) {
    const float* h      = (const float*)d_in[0];
    const int* mask     = (const int*)d_in[1];
    const float* ln_g   = (const float*)d_in[2];
    const float* ln_b   = (const float*)d_in[3];
    const float* W_out  = (const float*)d_in[4];
    const float* W_nm   = (const float*)d_in[5];
    const float* b_nm   = (const float*)d_in[6];
    const float* W_wg   = (const float*)d_in[7];
    const float* b_wg   = (const float*)d_in[8];
    float* out = (float*)d_out;

    char* ws = (char*)d_ws;
    // ---- region 0: Bpart (NOT zeroed — fully overwritten each chunk) ----
    float* Bpart = (float*)(ws);                                   // 112*CC*NS*4 = 3,670,016 B
    // ---- zeroed region: memS + Kvec + snap ----
    float* memS  = (float*)(ws + 8388608);                         // 1,835,008 B
    float* Kvec  = (float*)(ws + 8388608 + 1835008);               // 2,048 B
    float* snap  = (float*)(ws + 8388608 + 1835008 + 2048);        // 29,360,128 B
    const size_t Z0 = 8388608;
    const size_t ZBYTES = 1835008 + 2048 + 29360128;               // 31,197,184
    // ---- non-zeroed ----
    float* fbuf  = (float*)(ws + 8388608 + ZBYTES);                // 8,388,608
    float* wgbuf = (float*)(ws + 8388608 + ZBYTES + 8388608);      // 131,072
    int*   ssbuf = (int*)  (ws + 8388608 + ZBYTES + 8388608 + 131072);  // 131,072
    char*  Mreg  = ws + 8388608 + ZBYTES + 8388608 + 262144;       // 58,720,256 region
    float* Gd = (float*)(Mreg);                                    // 16,777,216
    float* R  = (float*)(Mreg + 16777216);
    float* Q  = (float*)(Mreg + 16777216 + 131072);
    float* P2 = (float*)(Mreg + 16777216 + 262144);
    __hip_bfloat16* Mbuf = (__hip_bfloat16*)Mreg;
    // bf16 W_out aliases the Bpart region (dead after the chain)
    __hip_bfloat16* Wb = (__hip_bfloat16*)(ws);                    // 1,605,632 B

    hipMemsetAsync(ws + Z0, 0, ZBYTES, stream);
    hipLaunchKernelGGL(k0_dots, dim3(BB * TT), dim3(64), 0, stream,
                       h, W_nm, W_wg, R, Q, P2);
    hipLaunchKernelGGL(kG_gram, dim3(BB * NC * 2), dim3(256), 0, stream, h, Gd);

    hipLaunchKernelGGL(kS_seq, dim3(BB), dim3(256), 0, stream,
                       Bpart, Gd, R, Q, P2, mask, b_nm, b_wg, W_wg,
                       Kvec, fbuf, wgbuf, ssbuf, 0);
    for (int c = 1; c < NC; ++c) {
        hipLaunchKernelGGL(kB_base, dim3(NSLICE, BB), dim3(256), 0, stream,
                           h, wgbuf, ssbuf, memS, snap, Bpart, c);
        hipLaunchKernelGGL(kS_seq, dim3(BB), dim3(256), 0, stream,
                           Bpart, Gd, R, Q, P2, mask, b_nm, b_wg, W_wg,
                           Kvec, fbuf, wgbuf, ssbuf, c);
    }

    hipLaunchKernelGGL(k1_wcvt, dim3(784), dim3(256), 0, stream, W_out, Wb);
    hipLaunchKernelGGL(k2_replay, dim3(BB * NRC * 2), dim3(448), 0, stream,
                       h, fbuf, wgbuf, ssbuf, snap, Mbuf);
    hipLaunchKernelGGL(k3_ln, dim3(BB * TT), dim3(64), 0, stream,
                       Mbuf, ln_g, ln_b);
    hipLaunchKernelGGL(k4_gemm, dim3(7, 256), dim3(256), 0, stream,
                       Mbuf, Wb, h, out);
}

// Round 11
// 3882.826 us; speedup vs baseline: 1.7210x; 1.7210x over previous
//
#include <hip/hip_runtime.h>
#include <hip/hip_bf16.h>

#define DIM 896
#define TT 4096
#define BB 8
#define NS 64           // slots
#define CC 128          // sequential chunk length
#define NC 32           // TT/CC
#define RCH 256         // replay chunk length (k2)
#define NRC 16          // TT/RCH
#define NSLICE 14       // dim slices in kB

typedef float floatx4 __attribute__((ext_vector_type(4)));
typedef short short8 __attribute__((ext_vector_type(8)));

// -------- DPP wave64 reductions (VALU, no DS pipe) --------
#define DPP_F(x_, ctrl_, rmask_, old_) \
  __int_as_float(__builtin_amdgcn_update_dpp(__float_as_int(old_), __float_as_int(x_), (ctrl_), (rmask_), 0xf, false))

__device__ __forceinline__ float wave_sum64(float x) {
    x += DPP_F(x, 0x111, 0xf, 0.0f);   // row_shr:1
    x += DPP_F(x, 0x112, 0xf, 0.0f);   // row_shr:2
    x += DPP_F(x, 0x114, 0xf, 0.0f);   // row_shr:4
    x += DPP_F(x, 0x118, 0xf, 0.0f);   // row_shr:8
    x += DPP_F(x, 0x142, 0xa, 0.0f);   // row_bcast:15 -> rows 1,3
    x += DPP_F(x, 0x143, 0xc, 0.0f);   // row_bcast:31 -> rows 2,3
    return __int_as_float(__builtin_amdgcn_readlane(__float_as_int(x), 63));
}
__device__ __forceinline__ float wave_max64(float x) {
    x = fmaxf(x, DPP_F(x, 0x111, 0xf, -INFINITY));
    x = fmaxf(x, DPP_F(x, 0x112, 0xf, -INFINITY));
    x = fmaxf(x, DPP_F(x, 0x114, 0xf, -INFINITY));
    x = fmaxf(x, DPP_F(x, 0x118, 0xf, -INFINITY));
    x = fmaxf(x, DPP_F(x, 0x142, 0xa, -INFINITY));
    x = fmaxf(x, DPP_F(x, 0x143, 0xc, -INFINITY));
    return __int_as_float(__builtin_amdgcn_readlane(__float_as_int(x), 63));
}

__device__ __forceinline__ float rfl_f(float x) {
    return __int_as_float(__builtin_amdgcn_readfirstlane(__float_as_int(x)));
}
__device__ __forceinline__ float rl_f(float x, int l) {
    return __int_as_float(__builtin_amdgcn_readlane(__float_as_int(x), l));
}

// ---------------- K0: per-token dots, 4 rows per block (one wave per row) ----------------
__global__ __launch_bounds__(256) void k0_dots(const float* __restrict__ h,
                                               const float* __restrict__ W_nm,
                                               const float* __restrict__ W_wg,
                                               float* __restrict__ R, float* __restrict__ Q,
                                               float* __restrict__ P2) {
    const int r = blockIdx.x * 4 + (threadIdx.x >> 6);
    const int lane = threadIdx.x & 63;
    const float2* hr = (const float2*)(h + (size_t)r * DIM);
    const float2* w0 = (const float2*)W_nm;
    const float2* w1 = (const float2*)(W_nm + DIM);
    const float2* w2 = (const float2*)W_wg;
    float a = 0.f, bsum = 0.f, c = 0.f;
    #pragma unroll
    for (int i = 0; i < 7; ++i) {
        int idx = lane + 64 * i;
        float2 hv = hr[idx];
        float2 a0 = w0[idx], a1 = w1[idx], a2 = w2[idx];
        a = fmaf(hv.x, a0.x, fmaf(hv.y, a0.y, a));
        bsum = fmaf(hv.x, a1.x, fmaf(hv.y, a1.y, bsum));
        c = fmaf(hv.x, a2.x, fmaf(hv.y, a2.y, c));
    }
    #pragma unroll
    for (int off = 32; off; off >>= 1) {
        a += __shfl_xor(a, off);
        bsum += __shfl_xor(bsum, off);
        c += __shfl_xor(c, off);
    }
    if (lane == 0) { R[r] = a; P2[r] = bsum; Q[r] = c; }
}

// ---------------- KG: per-chunk Gram diagonal blocks  G[tau][t'] = h_tau . h_t' ----------
__global__ __launch_bounds__(256) void kG_gram(const float* __restrict__ h,
                                               float* __restrict__ Gd) {
    const int blk = blockIdx.x;           // (b*NC + c)*2 + half
    const int bc = blk >> 1, half = blk & 1;
    const int b = bc / NC, c = bc % NC;
    const int tid = threadIdx.x;
    const int ti = tid >> 4, tj = tid & 15;
    __shared__ float Hs[32][132];
    float acc[8][4];
    #pragma unroll
    for (int u = 0; u < 8; u++)
        #pragma unroll
        for (int v = 0; v < 4; v++) acc[u][v] = 0.f;
    const size_t hb = (size_t)b * TT * DIM + (size_t)c * CC * DIM;
    for (int kb = 0; kb < 28; ++kb) {
        __syncthreads();
        #pragma unroll
        for (int l = 0; l < 4; ++l) {
            int idx = tid + l * 256;
            int r = idx >> 3, kq = idx & 7;
            float4 f = *(const float4*)&h[hb + (size_t)r * DIM + kb * 32 + kq * 4];
            Hs[kq * 4 + 0][r] = f.x; Hs[kq * 4 + 1][r] = f.y;
            Hs[kq * 4 + 2][r] = f.z; Hs[kq * 4 + 3][r] = f.w;
        }
        __syncthreads();
        #pragma unroll 4
        for (int k = 0; k < 32; ++k) {
            float4 a0 = *(const float4*)&Hs[k][ti * 8];
            float4 a1 = *(const float4*)&Hs[k][ti * 8 + 4];
            float4 bv = *(const float4*)&Hs[k][half * 64 + tj * 4];
            float av[8] = {a0.x, a0.y, a0.z, a0.w, a1.x, a1.y, a1.z, a1.w};
            float bb[4] = {bv.x, bv.y, bv.z, bv.w};
            #pragma unroll
            for (int u = 0; u < 8; u++)
                #pragma unroll
                for (int v = 0; v < 4; v++)
                    acc[u][v] = fmaf(av[u], bb[v], acc[u][v]);
        }
    }
    float* gp = Gd + (size_t)bc * CC * CC;
    #pragma unroll
    for (int u = 0; u < 8; u++) {
        float4 o = {acc[u][0], acc[u][1], acc[u][2], acc[u][3]};
        *(float4*)&gp[(size_t)(ti * 8 + u) * CC + half * 64 + tj * 4] = o;
    }
}

// ---------------- KB: fused mem-replay (chunk c-1) + Base partials for chunk c -----------
#define MC_(i) case i: mc[i] = fmaf(mc[i], om, wh); break;
__global__ __launch_bounds__(256) void kB_base(const float* __restrict__ h,
                                               const float* __restrict__ wgbuf,
                                               const int* __restrict__ ssbuf,
                                               float* __restrict__ memS,
                                               float* __restrict__ snap,
                                               float* __restrict__ Bpart,
                                               int c) {
    const int slice = blockIdx.x;
    const int b = blockIdx.y;
    const int tid = threadIdx.x;
    __shared__ float wsh[CC];
    __shared__ int   ssh[CC];
    __shared__ float Asb[64][65];     // [k within slice][s]
    __shared__ float Bsb[CC][65];     // [t'][k]

    if (tid < CC) {
        wsh[tid] = wgbuf[b * TT + (c - 1) * CC + tid];
        ssh[tid] = ssbuf[b * TT + (c - 1) * CC + tid];
    }
    const int q = tid >> 6, d = tid & 63;
    const int dg = slice * 64 + d;
    float mc[16];
    #pragma unroll
    for (int j = 0; j < 16; j++) mc[j] = memS[((size_t)b * NS + q * 16 + j) * DIM + dg];
    __syncthreads();

    const size_t hb = (size_t)b * TT * DIM + (size_t)((c - 1) * CC) * DIM + dg;
    float hv[16];
    #pragma unroll
    for (int j = 0; j < 16; ++j) hv[j] = h[hb + (size_t)j * DIM];
    for (int i0 = 0; i0 < CC; i0 += 16) {
        float hvn[16];
        if (i0 + 16 < CC) {
            #pragma unroll
            for (int j = 0; j < 16; ++j) hvn[j] = h[hb + (size_t)(i0 + 16 + j) * DIM];
        }
        #pragma unroll
        for (int j = 0; j < 16; ++j) {
            const int i = i0 + j;
            float hvv = hv[j];
            int ss = __builtin_amdgcn_readfirstlane(ssh[i]);   // block-uniform -> scalar switch
            float w = rfl_f(wsh[i]);
            if ((ss >> 4) == q) {
                float om = 1.f - w, wh = w * hvv;
                switch (ss & 15) {
                    MC_(0) MC_(1) MC_(2) MC_(3) MC_(4) MC_(5) MC_(6) MC_(7)
                    MC_(8) MC_(9) MC_(10) MC_(11) MC_(12) MC_(13) MC_(14) MC_(15)
                }
            }
        }
        #pragma unroll
        for (int j = 0; j < 16; ++j) hv[j] = hvn[j];
    }
    #pragma unroll
    for (int j = 0; j < 16; j++) {
        memS[((size_t)b * NS + q * 16 + j) * DIM + dg] = mc[j];
        Asb[d][q * 16 + j] = mc[j];
    }
    if ((c & 1) == 0) {
        const int r = c >> 1;
        #pragma unroll
        for (int j = 0; j < 16; j++)
            snap[(((size_t)b * NRC + r) * NS + q * 16 + j) * DIM + dg] = mc[j];
    }
    const size_t hb2 = (size_t)b * TT * DIM + (size_t)(c * CC) * DIM + slice * 64;
    for (int idx = tid; idx < CC * 64; idx += 256) {
        int tp = idx >> 6, k = idx & 63;
        Bsb[tp][k] = h[hb2 + (size_t)tp * DIM + k];
    }
    __syncthreads();

    const int tg = tid >> 3, sg = tid & 7;
    float acc[4][8];
    #pragma unroll
    for (int v = 0; v < 4; v++)
        #pragma unroll
        for (int u = 0; u < 8; u++) acc[v][u] = 0.f;
    #pragma unroll 4
    for (int k = 0; k < 64; ++k) {
        float bv[4], av[8];
        #pragma unroll
        for (int v = 0; v < 4; v++) bv[v] = Bsb[tg * 4 + v][k];
        #pragma unroll
        for (int u = 0; u < 8; u++) av[u] = Asb[k][sg * 8 + u];
        #pragma unroll
        for (int v = 0; v < 4; v++)
            #pragma unroll
            for (int u = 0; u < 8; u++)
                acc[v][u] = fmaf(bv[v], av[u], acc[v][u]);
    }
    float* bp = Bpart + ((size_t)(slice * BB + b)) * CC * NS;
    #pragma unroll
    for (int v = 0; v < 4; v++) {
        float4 o0 = {acc[v][0], acc[v][1], acc[v][2], acc[v][3]};
        float4 o1 = {acc[v][4], acc[v][5], acc[v][6], acc[v][7]};
        *(float4*)&bp[(size_t)(tg * 4 + v) * NS + sg * 8] = o0;
        *(float4*)&bp[(size_t)(tg * 4 + v) * NS + sg * 8 + 4] = o1;
    }
}

// ---------------- KS v5: LDS-staged Gd + branchless step body (proven R9/R10) ------------
#define SIDX(r, c_) (((r) << 6) + (((c_) ^ ((r) & 63))))
__global__ __launch_bounds__(256) void kS_seq(const float* __restrict__ Bpart,
                                              const float* __restrict__ Gd,
                                              const float* __restrict__ Rv,
                                              const float* __restrict__ Qv,
                                              const float* __restrict__ P2v,
                                              const int* __restrict__ mask,
                                              const float* __restrict__ b_nm,
                                              const float* __restrict__ b_wg,
                                              const float* __restrict__ W_wg,
                                              float* __restrict__ Kvec,
                                              float* __restrict__ fbuf,
                                              float* __restrict__ wgbuf,
                                              int* __restrict__ ssbuf,
                                              int c) {
    const int b = blockIdx.x;
    const int tid = threadIdx.x;
    const int lane = tid & 63;
    const int wv = tid >> 6;
    __shared__ float S[129 * 64];        // swizzled; row 128 = dummy sink
    __shared__ float Gb[2][17 * 128];    // 16-row bands + dummy row 16
    const int tb = b * TT + c * CC;
    const float* gdc = Gd + (size_t)(b * NC + c) * CC * CC;

    // ---- stage S (14-way Bpart reduce), all 4 waves ----
    if (c == 0) {
        for (int t = wv * 32; t < wv * 32 + 32; ++t) S[SIDX(t, lane)] = 0.f;
    } else {
        const float* bp0 = Bpart + (size_t)b * CC * NS;
        for (int t = wv * 32; t < wv * 32 + 32; ++t) {
            float s = 0.f;
            #pragma unroll
            for (int sl = 0; sl < NSLICE; ++sl)
                s += bp0[(size_t)sl * (BB * CC * NS) + (size_t)t * NS + lane];
            S[SIDX(t, lane)] = s;
        }
    }
    // ---- stage Gd band 0 (rows 0..15), all 4 waves ----
    for (int idx = tid; idx < 512; idx += 256) {
        int r = idx >> 5, cq = idx & 31;
        *(float4*)&Gb[0][r * 128 + cq * 4] = *(const float4*)&gdc[(size_t)r * CC + cq * 4];
    }

    // ---- wave0-only register state ----
    float cur = 0.f, p1 = 0.f, p2 = 0.f, p3 = 0.f, K = 0.f;
    float Rl0 = 0.f, Rl1 = 0.f, Ql0 = 0.f, Ql1 = 0.f;
    float Pl0 = 0.f, Pl1 = 0.f, Ml0 = 0.f, Ml1 = 0.f;
    float bnm = 0.f, bwg = 0.f, wD = 0.f;
    const float scale = 1.0f / sqrtf((float)DIM);
    if (wv == 0) {
        cur = S[SIDX(0, lane)];
        p1  = S[SIDX(1, lane)];
        p2  = S[SIDX(2, lane)];
        p3  = S[SIDX(3, lane)];
        K = Kvec[b * NS + lane];
        Rl0 = Rv[tb + lane];  Rl1 = Rv[tb + 64 + lane];
        Ql0 = Qv[tb + lane];  Ql1 = Qv[tb + 64 + lane];
        Pl0 = P2v[tb + lane]; Pl1 = P2v[tb + 64 + lane];
        Ml0 = (float)mask[tb + lane]; Ml1 = (float)mask[tb + 64 + lane];
        bnm = b_nm[0]; bwg = b_wg[0]; wD = W_wg[DIM];
    }
    __syncthreads();

    for (int bb = 0; bb < 8; ++bb) {
        if (wv == 0) {
            const int base = bb * 16;
            const float* gcur = Gb[bb & 1];
            const float Rb = (base & 64) ? Rl1 : Rl0;
            const float Qb = (base & 64) ? Ql1 : Ql0;
            const float Pb = (base & 64) ? Pl1 : Pl0;
            const float Mb = (base & 64) ? Ml1 : Ml0;
            float g0 = gcur[(base + 1 + lane) & 127];
            float g1 = gcur[(base + 65 + lane) & 127];
            #pragma unroll 4
            for (int s = 0; s < 16; ++s) {
                const int tau = base + s;
                float g0n = gcur[(s + 1) * 128 + ((tau + 2 + lane) & 127)];
                float g1n = gcur[(s + 1) * 128 + ((tau + 66 + lane) & 127)];
                int rp4 = tau + 4; rp4 = (rp4 > 128) ? 128 : rp4;
                float p4 = S[SIDX(rp4, lane)];
                const float Rt = rl_f(Rb, tau & 63);
                const float Qt = rl_f(Qb, tau & 63);
                const float Pt = rl_f(Pb, tau & 63);
                const float Mk = rl_f(Mb, tau & 63);

                float sco = cur * scale;
                float mv = wave_max64(sco);
                float e = __expf(sco);
                float se = wave_sum64(e);
                float sk = wave_sum64(e * K);
                unsigned long long bal = __ballot(sco == mv);
                int mi = (int)__ffsll(bal) - 1;             // lowest-index tie-break

                float inv = 1.f / se;
                fbuf[((size_t)tb + tau) * NS + lane] = e * inv;
                float gdot = sk * inv;
                float g = 1.f / (1.f + __expf(-(Rt + gdot + bnm)));
                float w = 1.f / (1.f + __expf(-(Qt + g * wD + bwg)));
                w = fminf(w, 0.2f) * Mk;
                if (lane == 0) {
                    wgbuf[tb + tau] = w;
                    ssbuf[tb + tau] = mi;
                }
                float om = 1.f - w;
                K = (lane == mi) ? fmaf(K, om, w * Pt) : K;

                int r1 = tau + 1 + lane;
                int ix1 = (lane >= 4 && r1 < 128) ? SIDX(r1, mi) : (128 * 64 + lane);
                int r2 = tau + 65 + lane;
                int ix2 = (r2 < 128) ? SIDX(r2, mi) : (128 * 64 + lane);
                S[ix1] = fmaf(S[ix1], om, w * g0);
                S[ix2] = fmaf(S[ix2], om, w * g1);

                const float q1 = rl_f(g0, 0), q2 = rl_f(g0, 1);
                const float q3 = rl_f(g0, 2), q4 = rl_f(g0, 3);
                const bool m_ = (lane == mi);
                p1 = m_ ? fmaf(p1, om, w * q1) : p1;
                p2 = m_ ? fmaf(p2, om, w * q2) : p2;
                p3 = m_ ? fmaf(p3, om, w * q3) : p3;
                p4 = m_ ? fmaf(p4, om, w * q4) : p4;
                cur = p1; p1 = p2; p2 = p3; p3 = p4;
                g0 = g0n; g1 = g1n;
            }
        } else if (bb < 7) {
            const int bs = (bb + 1) * 16;
            float* dst = Gb[(bb + 1) & 1];
            for (int idx = tid - 64; idx < 512; idx += 192) {
                int r = idx >> 5, cq = idx & 31;
                *(float4*)&dst[r * 128 + cq * 4] =
                    *(const float4*)&gdc[(size_t)(bs + r) * CC + cq * 4];
            }
        }
        __syncthreads();
    }
    if (wv == 0) Kvec[b * NS + lane] = K;
}

// ---------------- K1: convert W_out to bf16 once ----------------
__global__ __launch_bounds__(256) void k1_wcvt(const float* __restrict__ W,
                                               __hip_bfloat16* __restrict__ Wb) {
    const int idx = blockIdx.x * 256 + threadIdx.x;     // 0..200703 float4s
    const float4 f = ((const float4*)W)[idx];
    alignas(8) __hip_bfloat16 t[4];
    t[0] = __float2bfloat16(f.x); t[1] = __float2bfloat16(f.y);
    t[2] = __float2bfloat16(f.z); t[3] = __float2bfloat16(f.w);
    *(uint2*)&Wb[(size_t)idx * 4] = *(const uint2*)t;
}

// ---------------- K2: chunk-parallel replay -> m_t (bf16) — proven R7/R8 version ---------
#define CS_(i) case i: mem[i] = fmaf(mem[i], sA, aB); break;
__global__ __launch_bounds__(448) void k2_replay(const float* __restrict__ h,
                                                 const float* __restrict__ fbuf,
                                                 const float* __restrict__ wgbuf,
                                                 const int* __restrict__ ssbuf,
                                                 const float* __restrict__ snap,
                                                 __hip_bfloat16* __restrict__ Mbuf) {
    const int blk = blockIdx.x;          // 0..255 : ((b*16 + c)*2 + halfD)
    const int b = blk >> 5;
    const int c = (blk >> 1) & 15;
    const int halfD = blk & 1;
    const int tid = threadIdx.x;         // 0..447
    const int dg = halfD * 448 + tid;    // dim index

    __shared__ float lf[128 * NS];
    __shared__ float lwg[RCH];
    __shared__ int   lss[RCH];

    float mem[64];
    const float* sp = snap + (((size_t)b * NRC + c) * NS) * DIM + dg;
    #pragma unroll
    for (int s2 = 0; s2 < 64; s2++) mem[s2] = sp[(size_t)s2 * DIM];

    const int t0 = c * RCH;
    if (tid < RCH) {
        lwg[tid] = wgbuf[b * TT + t0 + tid];
        lss[tid] = ssbuf[b * TT + t0 + tid];
    }
    const size_t hbase = (size_t)b * TT * DIM + (size_t)t0 * DIM + dg;
    const size_t fbase = ((size_t)b * TT + t0) * NS;
    const size_t mrow = ((size_t)b * TT + t0) * DIM + dg;

    for (int half = 0; half < 2; ++half) {
        __syncthreads();
        const float4* src = (const float4*)(fbuf + fbase + (size_t)half * 128 * NS);
        for (int idx = tid; idx < 128 * NS / 4; idx += 448)
            ((float4*)lf)[idx] = src[idx];
        __syncthreads();

        float hv[8];
        #pragma unroll
        for (int j = 0; j < 8; ++j)
            hv[j] = h[hbase + (size_t)(half * 128 + j) * DIM];

        for (int tg = 0; tg < 128; tg += 8) {
            float hvn[8];
            if (tg + 8 < 128) {
                #pragma unroll
                for (int j = 0; j < 8; ++j)
                    hvn[j] = h[hbase + (size_t)(half * 128 + tg + 8 + j) * DIM];
            }
            #pragma unroll
            for (int j = 0; j < 8; ++j) {
                const int tl = tg + j;
                const int tt = half * 128 + tl;
                const float4* f4p = (const float4*)&lf[tl * NS];
                float m0 = 0.f, m1 = 0.f, m2 = 0.f, m3 = 0.f;
                #pragma unroll
                for (int qq = 0; qq < 16; qq++) {
                    float4 f4 = f4p[qq];
                    m0 = fmaf(f4.x, mem[4 * qq], m0);
                    m1 = fmaf(f4.y, mem[4 * qq + 1], m1);
                    m2 = fmaf(f4.z, mem[4 * qq + 2], m2);
                    m3 = fmaf(f4.w, mem[4 * qq + 3], m3);
                }
                Mbuf[mrow + (size_t)tt * DIM] = __float2bfloat16((m0 + m1) + (m2 + m3));
                int ss = __builtin_amdgcn_readfirstlane(lss[tt]);  // block-uniform
                float w = rfl_f(lwg[tt]);
                float sA = 1.0f - w, aB = w * hv[j];
                switch (ss) {
                    CS_(0) CS_(1) CS_(2) CS_(3) CS_(4) CS_(5) CS_(6) CS_(7)
                    CS_(8) CS_(9) CS_(10) CS_(11) CS_(12) CS_(13) CS_(14) CS_(15)
                    CS_(16) CS_(17) CS_(18) CS_(19) CS_(20) CS_(21) CS_(22) CS_(23)
                    CS_(24) CS_(25) CS_(26) CS_(27) CS_(28) CS_(29) CS_(30) CS_(31)
                    CS_(32) CS_(33) CS_(34) CS_(35) CS_(36) CS_(37) CS_(38) CS_(39)
                    CS_(40) CS_(41) CS_(42) CS_(43) CS_(44) CS_(45) CS_(46) CS_(47)
                    CS_(48) CS_(49) CS_(50) CS_(51) CS_(52) CS_(53) CS_(54) CS_(55)
                    CS_(56) CS_(57) CS_(58) CS_(59) CS_(60) CS_(61) CS_(62) CS_(63)
                }
            }
            #pragma unroll
            for (int j = 0; j < 8; ++j) hv[j] = hvn[j];
        }
    }
}

// ---------------- K3: row LayerNorm, 4 rows per block (one wave per row) -----------------
__global__ __launch_bounds__(256) void k3_ln(__hip_bfloat16* __restrict__ Mbuf,
                                             const float* __restrict__ ln_g,
                                             const float* __restrict__ ln_b) {
    const size_t r = (size_t)blockIdx.x * 4 + (threadIdx.x >> 6);
    const int lane = threadIdx.x & 63;
    __hip_bfloat162* row2 = (__hip_bfloat162*)(Mbuf + r * DIM);
    float vx[7], vy[7];
    float s1 = 0.f, s2 = 0.f;
    #pragma unroll
    for (int i = 0; i < 7; i++) {
        __hip_bfloat162 x2 = row2[lane + 64 * i];
        float x = __bfloat162float(x2.x), y = __bfloat162float(x2.y);
        vx[i] = x; vy[i] = y;
        s1 += x + y;
        s2 = fmaf(x, x, fmaf(y, y, s2));
    }
    #pragma unroll
    for (int off = 32; off; off >>= 1) {
        s1 += __shfl_xor(s1, off);
        s2 += __shfl_xor(s2, off);
    }
    float mu = s1 * (1.0f / DIM);
    float var = fmaxf(s2 * (1.0f / DIM) - mu * mu, 0.0f);
    float rs = 1.0f / sqrtf(var + 1e-5f);
    #pragma unroll
    for (int i = 0; i < 7; i++) {
        int d = 2 * (lane + 64 * i);
        float2 lg = *(const float2*)&ln_g[d];
        float2 lb = *(const float2*)&ln_b[d];
        __hip_bfloat162 o;
        o.x = __float2bfloat16((vx[i] - mu) * rs * lg.x + lb.x);
        o.y = __float2bfloat16((vy[i] - mu) * rs * lg.y + lb.y);
        row2[lane + 64 * i] = o;
    }
}

// ---------------- K4: out = h + clip(0.5 * MN @ W_out^T) (bf16 MFMA GEMM) ----------------
__global__ __launch_bounds__(256) void k4_gemm(const __hip_bfloat16* __restrict__ Mn,
                                               const __hip_bfloat16* __restrict__ Wb,
                                               const float* __restrict__ h,
                                               float* __restrict__ out) {
    const int nt = blockIdx.x;   // 0..6
    const int mt = blockIdx.y;   // 0..255
    const int tid = threadIdx.x;
    const int wave = tid >> 6, lane = tid & 63;
    const int wr = wave >> 1, wc = wave & 1;

    __shared__ __hip_bfloat16 Asb[128 * 72];
    __shared__ __hip_bfloat16 Bsb[128 * 72];

    floatx4 acc[4][4];
    #pragma unroll
    for (int i = 0; i < 4; i++)
        #pragma unroll
        for (int jn = 0; jn < 4; jn++)
            acc[i][jn] = (floatx4){0.f, 0.f, 0.f, 0.f};

    const int lrow = lane & 15;
    const int lk = (lane >> 4) * 8;
    const int rr = tid >> 3, ch = tid & 7;

    for (int kt = 0; kt < 14; ++kt) {
        #pragma unroll
        for (int it = 0; it < 4; ++it) {
            int row = rr + 32 * it;
            const uint4* srcA = (const uint4*)(Mn + ((size_t)(mt * 128 + row)) * DIM + kt * 64 + ch * 8);
            *(uint4*)&Asb[row * 72 + ch * 8] = *srcA;
            const uint4* srcB = (const uint4*)(Wb + ((size_t)(nt * 128 + row)) * DIM + kt * 64 + ch * 8);
            *(uint4*)&Bsb[row * 72 + ch * 8] = *srcB;
        }
        __syncthreads();
        #pragma unroll
        for (int kk = 0; kk < 2; ++kk) {
            short8 af[4], bfr[4];
            #pragma unroll
            for (int i = 0; i < 4; i++)
                af[i] = *(const short8*)&Asb[(wr * 64 + i * 16 + lrow) * 72 + kk * 32 + lk];
            #pragma unroll
            for (int i2 = 0; i2 < 4; i2++)
                bfr[i2] = *(const short8*)&Bsb[(wc * 64 + i2 * 16 + lrow) * 72 + kk * 32 + lk];
            #pragma unroll
            for (int i = 0; i < 4; i++)
                #pragma unroll
                for (int jn = 0; jn < 4; jn++)
                    acc[i][jn] = __builtin_amdgcn_mfma_f32_16x16x32_bf16(af[i], bfr[jn], acc[i][jn], 0, 0, 0);
        }
        __syncthreads();
    }
    const int crow = (lane >> 4) * 4, ccol = lane & 15;
    #pragma unroll
    for (int i = 0; i < 4; i++)
        #pragma unroll
        for (int jn = 0; jn < 4; jn++)
            #pragma unroll
            for (int rg = 0; rg < 4; rg++) {
                int rG = mt * 128 + wr * 64 + i * 16 + crow + rg;
                int nG = nt * 128 + wc * 64 + jn * 16 + ccol;
                size_t idx = (size_t)rG * DIM + nG;
                float d = acc[i][jn][rg] * 0.5f;
                d = fminf(fmaxf(d, -2.0f), 2.0f);
                out[idx] = h[idx] + d;
            }
}

extern "C" void kernel_launch(void* const* d_in, const int* in_sizes, int n_in,
                              void* d_out, int out_size, void* d_ws, size_t ws_size,
                              hipStream_t stream) {
    const float* h      = (const float*)d_in[0];
    const int* mask     = (const int*)d_in[1];
    const float* ln_g   = (const float*)d_in[2];
    const float* ln_b   = (const float*)d_in[3];
    const float* W_out  = (const float*)d_in[4];
    const float* W_nm   = (const float*)d_in[5];
    const float* b_nm   = (const float*)d_in[6];
    const float* W_wg   = (const float*)d_in[7];
    const float* b_wg   = (const float*)d_in[8];
    float* out = (float*)d_out;

    char* ws = (char*)d_ws;
    // ---- region 0: Bpart (NOT zeroed — fully overwritten each chunk) ----
    float* Bpart = (float*)(ws);                                   // 112*CC*NS*4 = 3,670,016 B
    // ---- zeroed region: memS + Kvec + snap ----
    float* memS  = (float*)(ws + 8388608);                         // 1,835,008 B
    float* Kvec  = (float*)(ws + 8388608 + 1835008);               // 2,048 B
    float* snap  = (float*)(ws + 8388608 + 1835008 + 2048);        // 29,360,128 B
    const size_t Z0 = 8388608;
    const size_t ZBYTES = 1835008 + 2048 + 29360128;               // 31,197,184
    // ---- non-zeroed ----
    float* fbuf  = (float*)(ws + 8388608 + ZBYTES);                // 8,388,608
    float* wgbuf = (float*)(ws + 8388608 + ZBYTES + 8388608);      // 131,072
    int*   ssbuf = (int*)  (ws + 8388608 + ZBYTES + 8388608 + 131072);  // 131,072
    char*  Mreg  = ws + 8388608 + ZBYTES + 8388608 + 262144;       // 58,720,256 region
    float* Gd = (float*)(Mreg);                                    // 16,777,216
    float* R  = (float*)(Mreg + 16777216);
    float* Q  = (float*)(Mreg + 16777216 + 131072);
    float* P2 = (float*)(Mreg + 16777216 + 262144);
    __hip_bfloat16* Mbuf = (__hip_bfloat16*)Mreg;
    // bf16 W_out aliases the Bpart region (dead after the chain)
    __hip_bfloat16* Wb = (__hip_bfloat16*)(ws);                    // 1,605,632 B

    hipMemsetAsync(ws + Z0, 0, ZBYTES, stream);
    hipLaunchKernelGGL(k0_dots, dim3(BB * TT / 4), dim3(256), 0, stream,
                       h, W_nm, W_wg, R, Q, P2);
    hipLaunchKernelGGL(kG_gram, dim3(BB * NC * 2), dim3(256), 0, stream, h, Gd);

    hipLaunchKernelGGL(kS_seq, dim3(BB), dim3(256), 0, stream,
                       Bpart, Gd, R, Q, P2, mask, b_nm, b_wg, W_wg,
                       Kvec, fbuf, wgbuf, ssbuf, 0);
    for (int c = 1; c < NC; ++c) {
        hipLaunchKernelGGL(kB_base, dim3(NSLICE, BB), dim3(256), 0, stream,
                           h, wgbuf, ssbuf, memS, snap, Bpart, c);
        hipLaunchKernelGGL(kS_seq, dim3(BB), dim3(256), 0, stream,
                           Bpart, Gd, R, Q, P2, mask, b_nm, b_wg, W_wg,
                           Kvec, fbuf, wgbuf, ssbuf, c);
    }

    hipLaunchKernelGGL(k1_wcvt, dim3(784), dim3(256), 0, stream, W_out, Wb);
    hipLaunchKernelGGL(k2_replay, dim3(BB * NRC * 2), dim3(448), 0, stream,
                       h, fbuf, wgbuf, ssbuf, snap, Mbuf);
    hipLaunchKernelGGL(k3_ln, dim3(BB * TT / 4), dim3(256), 0, stream,
                       Mbuf, ln_g, ln_b);
    hipLaunchKernelGGL(k4_gemm, dim3(7, 256), dim3(256), 0, stream,
                       Mbuf, Wb, h, out);
}

// Round 12
// 3808.440 us; speedup vs baseline: 1.7547x; 1.0195x over previous
//
#include <hip/hip_runtime.h>
#include <hip/hip_bf16.h>

#define DIM 896
#define TT 4096
#define BB 8
#define NS 64           // slots
#define CC 128          // sequential chunk length
#define NC 32           // TT/CC
#define RCH 256         // replay chunk length (k2)
#define NRC 16          // TT/RCH
#define NSLICE 14       // dim slices in kB

typedef float floatx4 __attribute__((ext_vector_type(4)));
typedef short short8 __attribute__((ext_vector_type(8)));

// -------- DPP wave64 reductions (VALU, no DS pipe) --------
#define DPP_F(x_, ctrl_, rmask_, old_) \
  __int_as_float(__builtin_amdgcn_update_dpp(__float_as_int(old_), __float_as_int(x_), (ctrl_), (rmask_), 0xf, false))

__device__ __forceinline__ float wave_sum64(float x) {
    x += DPP_F(x, 0x111, 0xf, 0.0f);   // row_shr:1
    x += DPP_F(x, 0x112, 0xf, 0.0f);   // row_shr:2
    x += DPP_F(x, 0x114, 0xf, 0.0f);   // row_shr:4
    x += DPP_F(x, 0x118, 0xf, 0.0f);   // row_shr:8
    x += DPP_F(x, 0x142, 0xa, 0.0f);   // row_bcast:15 -> rows 1,3
    x += DPP_F(x, 0x143, 0xc, 0.0f);   // row_bcast:31 -> rows 2,3
    return __int_as_float(__builtin_amdgcn_readlane(__float_as_int(x), 63));
}
__device__ __forceinline__ float wave_max64(float x) {
    x = fmaxf(x, DPP_F(x, 0x111, 0xf, -INFINITY));
    x = fmaxf(x, DPP_F(x, 0x112, 0xf, -INFINITY));
    x = fmaxf(x, DPP_F(x, 0x114, 0xf, -INFINITY));
    x = fmaxf(x, DPP_F(x, 0x118, 0xf, -INFINITY));
    x = fmaxf(x, DPP_F(x, 0x142, 0xa, -INFINITY));
    x = fmaxf(x, DPP_F(x, 0x143, 0xc, -INFINITY));
    return __int_as_float(__builtin_amdgcn_readlane(__float_as_int(x), 63));
}

__device__ __forceinline__ float rfl_f(float x) {
    return __int_as_float(__builtin_amdgcn_readfirstlane(__float_as_int(x)));
}
__device__ __forceinline__ float rl_f(float x, int l) {
    return __int_as_float(__builtin_amdgcn_readlane(__float_as_int(x), l));
}

// ---------------- K0: per-token dots, 4 rows per block (one wave per row) ----------------
__global__ __launch_bounds__(256) void k0_dots(const float* __restrict__ h,
                                               const float* __restrict__ W_nm,
                                               const float* __restrict__ W_wg,
                                               float* __restrict__ R, float* __restrict__ Q,
                                               float* __restrict__ P2) {
    const int r = blockIdx.x * 4 + (threadIdx.x >> 6);
    const int lane = threadIdx.x & 63;
    const float2* hr = (const float2*)(h + (size_t)r * DIM);
    const float2* w0 = (const float2*)W_nm;
    const float2* w1 = (const float2*)(W_nm + DIM);
    const float2* w2 = (const float2*)W_wg;
    float a = 0.f, bsum = 0.f, c = 0.f;
    #pragma unroll
    for (int i = 0; i < 7; ++i) {
        int idx = lane + 64 * i;
        float2 hv = hr[idx];
        float2 a0 = w0[idx], a1 = w1[idx], a2 = w2[idx];
        a = fmaf(hv.x, a0.x, fmaf(hv.y, a0.y, a));
        bsum = fmaf(hv.x, a1.x, fmaf(hv.y, a1.y, bsum));
        c = fmaf(hv.x, a2.x, fmaf(hv.y, a2.y, c));
    }
    #pragma unroll
    for (int off = 32; off; off >>= 1) {
        a += __shfl_xor(a, off);
        bsum += __shfl_xor(bsum, off);
        c += __shfl_xor(c, off);
    }
    if (lane == 0) { R[r] = a; P2[r] = bsum; Q[r] = c; }
}

// ---------------- KG v3: Gram blocks, conflict-free swizzled LDS -------------------------
// Staging: Hs[k][r ^ ((k&3)<<3)] (swizzle bijective per 8-col group; float4-safe).
// Writes: 64 distinct rows/wave -> 2-way (free). Reads: broadcast / 2-way (free).
__global__ __launch_bounds__(256) void kG_gram(const float* __restrict__ h,
                                               float* __restrict__ Gd) {
    const int blk = blockIdx.x;           // (b*NC + c)*2 + half
    const int bc = blk >> 1, half = blk & 1;
    const int b = bc / NC, c = bc % NC;
    const int tid = threadIdx.x;
    const int ti = tid >> 4, tj = tid & 15;
    __shared__ float Hs[32 * 128];
    float acc[8][4];
    #pragma unroll
    for (int u = 0; u < 8; u++)
        #pragma unroll
        for (int v = 0; v < 4; v++) acc[u][v] = 0.f;
    const size_t hb = (size_t)b * TT * DIM + (size_t)c * CC * DIM;
    for (int kb = 0; kb < 28; ++kb) {
        __syncthreads();
        #pragma unroll
        for (int l = 0; l < 4; ++l) {
            int idx = tid + l * 256;      // 0..1023
            int r = idx & 127, kq = idx >> 7;   // 128 rows x 8 k-quads
            float4 f = *(const float4*)&h[hb + (size_t)r * DIM + kb * 32 + kq * 4];
            Hs[(kq * 4 + 0) * 128 + (r ^ (((kq * 4 + 0) & 3) << 3))] = f.x;
            Hs[(kq * 4 + 1) * 128 + (r ^ (((kq * 4 + 1) & 3) << 3))] = f.y;
            Hs[(kq * 4 + 2) * 128 + (r ^ (((kq * 4 + 2) & 3) << 3))] = f.z;
            Hs[(kq * 4 + 3) * 128 + (r ^ (((kq * 4 + 3) & 3) << 3))] = f.w;
        }
        __syncthreads();
        #pragma unroll 4
        for (int k = 0; k < 32; ++k) {
            const int sw = (k & 3) << 3;
            float4 a0 = *(const float4*)&Hs[k * 128 + ((ti * 8) ^ sw)];
            float4 a1 = *(const float4*)&Hs[k * 128 + ((ti * 8 + 4) ^ sw)];
            float4 bv = *(const float4*)&Hs[k * 128 + ((half * 64 + tj * 4) ^ sw)];
            float av[8] = {a0.x, a0.y, a0.z, a0.w, a1.x, a1.y, a1.z, a1.w};
            float bb[4] = {bv.x, bv.y, bv.z, bv.w};
            #pragma unroll
            for (int u = 0; u < 8; u++)
                #pragma unroll
                for (int v = 0; v < 4; v++)
                    acc[u][v] = fmaf(av[u], bb[v], acc[u][v]);
        }
    }
    float* gp = Gd + (size_t)bc * CC * CC;
    #pragma unroll
    for (int u = 0; u < 8; u++) {
        float4 o = {acc[u][0], acc[u][1], acc[u][2], acc[u][3]};
        *(float4*)&gp[(size_t)(ti * 8 + u) * CC + half * 64 + tj * 4] = o;
    }
}

// ---------------- KB: fused mem-replay (chunk c-1) + Base partials for chunk c -----------
#define MC_(i) case i: mc[i] = fmaf(mc[i], om, wh); break;
__global__ __launch_bounds__(256) void kB_base(const float* __restrict__ h,
                                               const float* __restrict__ wgbuf,
                                               const int* __restrict__ ssbuf,
                                               float* __restrict__ memS,
                                               float* __restrict__ snap,
                                               float* __restrict__ Bpart,
                                               int c) {
    const int slice = blockIdx.x;
    const int b = blockIdx.y;
    const int tid = threadIdx.x;
    __shared__ float wsh[CC];
    __shared__ int   ssh[CC];
    __shared__ float Asb[64][65];     // [k within slice][s]
    __shared__ float Bsb[CC][65];     // [t'][k]

    if (tid < CC) {
        wsh[tid] = wgbuf[b * TT + (c - 1) * CC + tid];
        ssh[tid] = ssbuf[b * TT + (c - 1) * CC + tid];
    }
    const int q = tid >> 6, d = tid & 63;
    const int dg = slice * 64 + d;
    float mc[16];
    #pragma unroll
    for (int j = 0; j < 16; j++) mc[j] = memS[((size_t)b * NS + q * 16 + j) * DIM + dg];
    __syncthreads();

    const size_t hb = (size_t)b * TT * DIM + (size_t)((c - 1) * CC) * DIM + dg;
    float hv[16];
    #pragma unroll
    for (int j = 0; j < 16; ++j) hv[j] = h[hb + (size_t)j * DIM];
    for (int i0 = 0; i0 < CC; i0 += 16) {
        float hvn[16];
        if (i0 + 16 < CC) {
            #pragma unroll
            for (int j = 0; j < 16; ++j) hvn[j] = h[hb + (size_t)(i0 + 16 + j) * DIM];
        }
        #pragma unroll
        for (int j = 0; j < 16; ++j) {
            const int i = i0 + j;
            float hvv = hv[j];
            int ss = __builtin_amdgcn_readfirstlane(ssh[i]);   // block-uniform -> scalar switch
            float w = rfl_f(wsh[i]);
            if ((ss >> 4) == q) {
                float om = 1.f - w, wh = w * hvv;
                switch (ss & 15) {
                    MC_(0) MC_(1) MC_(2) MC_(3) MC_(4) MC_(5) MC_(6) MC_(7)
                    MC_(8) MC_(9) MC_(10) MC_(11) MC_(12) MC_(13) MC_(14) MC_(15)
                }
            }
        }
        #pragma unroll
        for (int j = 0; j < 16; ++j) hv[j] = hvn[j];
    }
    #pragma unroll
    for (int j = 0; j < 16; j++) {
        memS[((size_t)b * NS + q * 16 + j) * DIM + dg] = mc[j];
        Asb[d][q * 16 + j] = mc[j];
    }
    if ((c & 1) == 0) {
        const int r = c >> 1;
        #pragma unroll
        for (int j = 0; j < 16; j++)
            snap[(((size_t)b * NRC + r) * NS + q * 16 + j) * DIM + dg] = mc[j];
    }
    const size_t hb2 = (size_t)b * TT * DIM + (size_t)(c * CC) * DIM + slice * 64;
    for (int idx = tid; idx < CC * 64; idx += 256) {
        int tp = idx >> 6, k = idx & 63;
        Bsb[tp][k] = h[hb2 + (size_t)tp * DIM + k];
    }
    __syncthreads();

    const int tg = tid >> 3, sg = tid & 7;
    float acc[4][8];
    #pragma unroll
    for (int v = 0; v < 4; v++)
        #pragma unroll
        for (int u = 0; u < 8; u++) acc[v][u] = 0.f;
    #pragma unroll 4
    for (int k = 0; k < 64; ++k) {
        float bv[4], av[8];
        #pragma unroll
        for (int v = 0; v < 4; v++) bv[v] = Bsb[tg * 4 + v][k];
        #pragma unroll
        for (int u = 0; u < 8; u++) av[u] = Asb[k][sg * 8 + u];
        #pragma unroll
        for (int v = 0; v < 4; v++)
            #pragma unroll
            for (int u = 0; u < 8; u++)
                acc[v][u] = fmaf(bv[v], av[u], acc[v][u]);
    }
    float* bp = Bpart + ((size_t)(slice * BB + b)) * CC * NS;
    #pragma unroll
    for (int v = 0; v < 4; v++) {
        float4 o0 = {acc[v][0], acc[v][1], acc[v][2], acc[v][3]};
        float4 o1 = {acc[v][4], acc[v][5], acc[v][6], acc[v][7]};
        *(float4*)&bp[(size_t)(tg * 4 + v) * NS + sg * 8] = o0;
        *(float4*)&bp[(size_t)(tg * 4 + v) * NS + sg * 8 + 4] = o1;
    }
}

// ---------------- KS v6: v5 + early-issued RMW loads (wait overlapped) -------------------
#define SIDX(r, c_) (((r) << 6) + (((c_) ^ ((r) & 63))))
__global__ __launch_bounds__(256) void kS_seq(const float* __restrict__ Bpart,
                                              const float* __restrict__ Gd,
                                              const float* __restrict__ Rv,
                                              const float* __restrict__ Qv,
                                              const float* __restrict__ P2v,
                                              const int* __restrict__ mask,
                                              const float* __restrict__ b_nm,
                                              const float* __restrict__ b_wg,
                                              const float* __restrict__ W_wg,
                                              float* __restrict__ Kvec,
                                              float* __restrict__ fbuf,
                                              float* __restrict__ wgbuf,
                                              int* __restrict__ ssbuf,
                                              int c) {
    const int b = blockIdx.x;
    const int tid = threadIdx.x;
    const int lane = tid & 63;
    const int wv = tid >> 6;
    __shared__ float S[129 * 64];        // swizzled; row 128 = dummy sink
    __shared__ float Gb[2][17 * 128];    // 16-row bands + dummy row 16
    const int tb = b * TT + c * CC;
    const float* gdc = Gd + (size_t)(b * NC + c) * CC * CC;

    // ---- stage S (14-way Bpart reduce), all 4 waves ----
    if (c == 0) {
        for (int t = wv * 32; t < wv * 32 + 32; ++t) S[SIDX(t, lane)] = 0.f;
    } else {
        const float* bp0 = Bpart + (size_t)b * CC * NS;
        for (int t = wv * 32; t < wv * 32 + 32; ++t) {
            float s = 0.f;
            #pragma unroll
            for (int sl = 0; sl < NSLICE; ++sl)
                s += bp0[(size_t)sl * (BB * CC * NS) + (size_t)t * NS + lane];
            S[SIDX(t, lane)] = s;
        }
    }
    // ---- stage Gd band 0 (rows 0..15), all 4 waves ----
    for (int idx = tid; idx < 512; idx += 256) {
        int r = idx >> 5, cq = idx & 31;
        *(float4*)&Gb[0][r * 128 + cq * 4] = *(const float4*)&gdc[(size_t)r * CC + cq * 4];
    }

    // ---- wave0-only register state ----
    float cur = 0.f, p1 = 0.f, p2 = 0.f, p3 = 0.f, K = 0.f;
    float Rl0 = 0.f, Rl1 = 0.f, Ql0 = 0.f, Ql1 = 0.f;
    float Pl0 = 0.f, Pl1 = 0.f, Ml0 = 0.f, Ml1 = 0.f;
    float bnm = 0.f, bwg = 0.f, wD = 0.f;
    const float scale = 1.0f / sqrtf((float)DIM);
    if (wv == 0) {
        cur = S[SIDX(0, lane)];
        p1  = S[SIDX(1, lane)];
        p2  = S[SIDX(2, lane)];
        p3  = S[SIDX(3, lane)];
        K = Kvec[b * NS + lane];
        Rl0 = Rv[tb + lane];  Rl1 = Rv[tb + 64 + lane];
        Ql0 = Qv[tb + lane];  Ql1 = Qv[tb + 64 + lane];
        Pl0 = P2v[tb + lane]; Pl1 = P2v[tb + 64 + lane];
        Ml0 = (float)mask[tb + lane]; Ml1 = (float)mask[tb + 64 + lane];
        bnm = b_nm[0]; bwg = b_wg[0]; wD = W_wg[DIM];
    }
    __syncthreads();

    for (int bb = 0; bb < 8; ++bb) {
        if (wv == 0) {
            const int base = bb * 16;
            const float* gcur = Gb[bb & 1];
            const float Rb = (base & 64) ? Rl1 : Rl0;
            const float Qb = (base & 64) ? Ql1 : Ql0;
            const float Pb = (base & 64) ? Pl1 : Pl0;
            const float Mb = (base & 64) ? Ml1 : Ml0;
            float g0 = gcur[(base + 1 + lane) & 127];
            float g1 = gcur[(base + 65 + lane) & 127];
            #pragma unroll 4
            for (int s = 0; s < 16; ++s) {
                const int tau = base + s;
                float g0n = gcur[(s + 1) * 128 + ((tau + 2 + lane) & 127)];
                float g1n = gcur[(s + 1) * 128 + ((tau + 66 + lane) & 127)];
                int rp4 = tau + 4; rp4 = (rp4 > 128) ? 128 : rp4;
                float p4 = S[SIDX(rp4, lane)];
                const float Rt = rl_f(Rb, tau & 63);
                const float Qt = rl_f(Qb, tau & 63);
                const float Pt = rl_f(Pb, tau & 63);
                const float Mk = rl_f(Mb, tau & 63);

                float sco = cur * scale;
                float mv = wave_max64(sco);
                float e = __expf(sco);
                float se = wave_sum64(e);
                float sk = wave_sum64(e * K);
                unsigned long long bal = __ballot(sco == mv);
                int mi = (int)__ffsll(bal) - 1;             // lowest-index tie-break

                // early-issue RMW loads; their wait overlaps the sigmoid chain below
                int r1 = tau + 1 + lane;
                int ix1 = (lane >= 4 && r1 < 128) ? SIDX(r1, mi) : (128 * 64 + lane);
                int r2 = tau + 65 + lane;
                int ix2 = (r2 < 128) ? SIDX(r2, mi) : (128 * 64 + lane);
                float s1v = S[ix1];
                float s2v = S[ix2];

                float inv = 1.f / se;
                fbuf[((size_t)tb + tau) * NS + lane] = e * inv;
                float gdot = sk * inv;
                float g = 1.f / (1.f + __expf(-(Rt + gdot + bnm)));
                float w = 1.f / (1.f + __expf(-(Qt + g * wD + bwg)));
                w = fminf(w, 0.2f) * Mk;
                if (lane == 0) {
                    wgbuf[tb + tau] = w;
                    ssbuf[tb + tau] = mi;
                }
                float om = 1.f - w;
                K = (lane == mi) ? fmaf(K, om, w * Pt) : K;

                const float q1 = rl_f(g0, 0), q2 = rl_f(g0, 1);
                const float q3 = rl_f(g0, 2), q4 = rl_f(g0, 3);
                const bool m_ = (lane == mi);
                p1 = m_ ? fmaf(p1, om, w * q1) : p1;
                p2 = m_ ? fmaf(p2, om, w * q2) : p2;
                p3 = m_ ? fmaf(p3, om, w * q3) : p3;
                p4 = m_ ? fmaf(p4, om, w * q4) : p4;
                cur = p1; p1 = p2; p2 = p3; p3 = p4;

                // deferred RMW writes (in-order DS queue keeps next-step reads correct)
                S[ix1] = fmaf(s1v, om, w * g0);
                S[ix2] = fmaf(s2v, om, w * g1);
                g0 = g0n; g1 = g1n;
            }
        } else if (bb < 7) {
            const int bs = (bb + 1) * 16;
            float* dst = Gb[(bb + 1) & 1];
            for (int idx = tid - 64; idx < 512; idx += 192) {
                int r = idx >> 5, cq = idx & 31;
                *(float4*)&dst[r * 128 + cq * 4] =
                    *(const float4*)&gdc[(size_t)(bs + r) * CC + cq * 4];
            }
        }
        __syncthreads();
    }
    if (wv == 0) Kvec[b * NS + lane] = K;
}

// ---------------- K1: convert W_out to bf16 once ----------------
__global__ __launch_bounds__(256) void k1_wcvt(const float* __restrict__ W,
                                               __hip_bfloat16* __restrict__ Wb) {
    const int idx = blockIdx.x * 256 + threadIdx.x;     // 0..200703 float4s
    const float4 f = ((const float4*)W)[idx];
    alignas(8) __hip_bfloat16 t[4];
    t[0] = __float2bfloat16(f.x); t[1] = __float2bfloat16(f.y);
    t[2] = __float2bfloat16(f.z); t[3] = __float2bfloat16(f.w);
    *(uint2*)&Wb[(size_t)idx * 4] = *(const uint2*)t;
}

// ---------------- K2: chunk-parallel replay -> m_t (bf16) — R8 body + c==0 zero-init -----
#define CS_(i) case i: mem[i] = fmaf(mem[i], sA, aB); break;
__global__ __launch_bounds__(448) void k2_replay(const float* __restrict__ h,
                                                 const float* __restrict__ fbuf,
                                                 const float* __restrict__ wgbuf,
                                                 const int* __restrict__ ssbuf,
                                                 const float* __restrict__ snap,
                                                 __hip_bfloat16* __restrict__ Mbuf) {
    const int blk = blockIdx.x;          // 0..255 : ((b*16 + c)*2 + halfD)
    const int b = blk >> 5;
    const int c = (blk >> 1) & 15;
    const int halfD = blk & 1;
    const int tid = threadIdx.x;         // 0..447
    const int dg = halfD * 448 + tid;    // dim index

    __shared__ float lf[128 * NS];
    __shared__ float lwg[RCH];
    __shared__ int   lss[RCH];

    float mem[64];
    if (c == 0) {
        #pragma unroll
        for (int s2 = 0; s2 < 64; s2++) mem[s2] = 0.f;   // r=0 snapshot is the zero state
    } else {
        const float* sp = snap + (((size_t)b * NRC + c) * NS) * DIM + dg;
        #pragma unroll
        for (int s2 = 0; s2 < 64; s2++) mem[s2] = sp[(size_t)s2 * DIM];
    }

    const int t0 = c * RCH;
    if (tid < RCH) {
        lwg[tid] = wgbuf[b * TT + t0 + tid];
        lss[tid] = ssbuf[b * TT + t0 + tid];
    }
    const size_t hbase = (size_t)b * TT * DIM + (size_t)t0 * DIM + dg;
    const size_t fbase = ((size_t)b * TT + t0) * NS;
    const size_t mrow = ((size_t)b * TT + t0) * DIM + dg;

    for (int half = 0; half < 2; ++half) {
        __syncthreads();
        const float4* src = (const float4*)(fbuf + fbase + (size_t)half * 128 * NS);
        for (int idx = tid; idx < 128 * NS / 4; idx += 448)
            ((float4*)lf)[idx] = src[idx];
        __syncthreads();

        float hv[8];
        #pragma unroll
        for (int j = 0; j < 8; ++j)
            hv[j] = h[hbase + (size_t)(half * 128 + j) * DIM];

        for (int tg = 0; tg < 128; tg += 8) {
            float hvn[8];
            if (tg + 8 < 128) {
                #pragma unroll
                for (int j = 0; j < 8; ++j)
                    hvn[j] = h[hbase + (size_t)(half * 128 + tg + 8 + j) * DIM];
            }
            #pragma unroll
            for (int j = 0; j < 8; ++j) {
                const int tl = tg + j;
                const int tt = half * 128 + tl;
                const float4* f4p = (const float4*)&lf[tl * NS];
                float m0 = 0.f, m1 = 0.f, m2 = 0.f, m3 = 0.f;
                #pragma unroll
                for (int qq = 0; qq < 16; qq++) {
                    float4 f4 = f4p[qq];
                    m0 = fmaf(f4.x, mem[4 * qq], m0);
                    m1 = fmaf(f4.y, mem[4 * qq + 1], m1);
                    m2 = fmaf(f4.z, mem[4 * qq + 2], m2);
                    m3 = fmaf(f4.w, mem[4 * qq + 3], m3);
                }
                Mbuf[mrow + (size_t)tt * DIM] = __float2bfloat16((m0 + m1) + (m2 + m3));
                int ss = __builtin_amdgcn_readfirstlane(lss[tt]);  // block-uniform
                float w = rfl_f(lwg[tt]);
                float sA = 1.0f - w, aB = w * hv[j];
                switch (ss) {
                    CS_(0) CS_(1) CS_(2) CS_(3) CS_(4) CS_(5) CS_(6) CS_(7)
                    CS_(8) CS_(9) CS_(10) CS_(11) CS_(12) CS_(13) CS_(14) CS_(15)
                    CS_(16) CS_(17) CS_(18) CS_(19) CS_(20) CS_(21) CS_(22) CS_(23)
                    CS_(24) CS_(25) CS_(26) CS_(27) CS_(28) CS_(29) CS_(30) CS_(31)
                    CS_(32) CS_(33) CS_(34) CS_(35) CS_(36) CS_(37) CS_(38) CS_(39)
                    CS_(40) CS_(41) CS_(42) CS_(43) CS_(44) CS_(45) CS_(46) CS_(47)
                    CS_(48) CS_(49) CS_(50) CS_(51) CS_(52) CS_(53) CS_(54) CS_(55)
                    CS_(56) CS_(57) CS_(58) CS_(59) CS_(60) CS_(61) CS_(62) CS_(63)
                }
            }
            #pragma unroll
            for (int j = 0; j < 8; ++j) hv[j] = hvn[j];
        }
    }
}

// ---------------- K3: row LayerNorm, 4 rows per block (one wave per row) -----------------
__global__ __launch_bounds__(256) void k3_ln(__hip_bfloat16* __restrict__ Mbuf,
                                             const float* __restrict__ ln_g,
                                             const float* __restrict__ ln_b) {
    const size_t r = (size_t)blockIdx.x * 4 + (threadIdx.x >> 6);
    const int lane = threadIdx.x & 63;
    __hip_bfloat162* row2 = (__hip_bfloat162*)(Mbuf + r * DIM);
    float vx[7], vy[7];
    float s1 = 0.f, s2 = 0.f;
    #pragma unroll
    for (int i = 0; i < 7; i++) {
        __hip_bfloat162 x2 = row2[lane + 64 * i];
        float x = __bfloat162float(x2.x), y = __bfloat162float(x2.y);
        vx[i] = x; vy[i] = y;
        s1 += x + y;
        s2 = fmaf(x, x, fmaf(y, y, s2));
    }
    #pragma unroll
    for (int off = 32; off; off >>= 1) {
        s1 += __shfl_xor(s1, off);
        s2 += __shfl_xor(s2, off);
    }
    float mu = s1 * (1.0f / DIM);
    float var = fmaxf(s2 * (1.0f / DIM) - mu * mu, 0.0f);
    float rs = 1.0f / sqrtf(var + 1e-5f);
    #pragma unroll
    for (int i = 0; i < 7; i++) {
        int d = 2 * (lane + 64 * i);
        float2 lg = *(const float2*)&ln_g[d];
        float2 lb = *(const float2*)&ln_b[d];
        __hip_bfloat162 o;
        o.x = __float2bfloat16((vx[i] - mu) * rs * lg.x + lb.x);
        o.y = __float2bfloat16((vy[i] - mu) * rs * lg.y + lb.y);
        row2[lane + 64 * i] = o;
    }
}

// ---------------- K4: out = h + clip(0.5 * MN @ W_out^T) (bf16 MFMA GEMM) ----------------
__global__ __launch_bounds__(256) void k4_gemm(const __hip_bfloat16* __restrict__ Mn,
                                               const __hip_bfloat16* __restrict__ Wb,
                                               const float* __restrict__ h,
                                               float* __restrict__ out) {
    const int nt = blockIdx.x;   // 0..6
    const int mt = blockIdx.y;   // 0..255
    const int tid = threadIdx.x;
    const int wave = tid >> 6, lane = tid & 63;
    const int wr = wave >> 1, wc = wave & 1;

    __shared__ __hip_bfloat16 Asb[128 * 72];
    __shared__ __hip_bfloat16 Bsb[128 * 72];

    floatx4 acc[4][4];
    #pragma unroll
    for (int i = 0; i < 4; i++)
        #pragma unroll
        for (int jn = 0; jn < 4; jn++)
            acc[i][jn] = (floatx4){0.f, 0.f, 0.f, 0.f};

    const int lrow = lane & 15;
    const int lk = (lane >> 4) * 8;
    const int rr = tid >> 3, ch = tid & 7;

    for (int kt = 0; kt < 14; ++kt) {
        #pragma unroll
        for (int it = 0; it < 4; ++it) {
            int row = rr + 32 * it;
            const uint4* srcA = (const uint4*)(Mn + ((size_t)(mt * 128 + row)) * DIM + kt * 64 + ch * 8);
            *(uint4*)&Asb[row * 72 + ch * 8] = *srcA;
            const uint4* srcB = (const uint4*)(Wb + ((size_t)(nt * 128 + row)) * DIM + kt * 64 + ch * 8);
            *(uint4*)&Bsb[row * 72 + ch * 8] = *srcB;
        }
        __syncthreads();
        #pragma unroll
        for (int kk = 0; kk < 2; ++kk) {
            short8 af[4], bfr[4];
            #pragma unroll
            for (int i = 0; i < 4; i++)
                af[i] = *(const short8*)&Asb[(wr * 64 + i * 16 + lrow) * 72 + kk * 32 + lk];
            #pragma unroll
            for (int i2 = 0; i2 < 4; i2++)
                bfr[i2] = *(const short8*)&Bsb[(wc * 64 + i2 * 16 + lrow) * 72 + kk * 32 + lk];
            #pragma unroll
            for (int i = 0; i < 4; i++)
                #pragma unroll
                for (int jn = 0; jn < 4; jn++)
                    acc[i][jn] = __builtin_amdgcn_mfma_f32_16x16x32_bf16(af[i], bfr[jn], acc[i][jn], 0, 0, 0);
        }
        __syncthreads();
    }
    const int crow = (lane >> 4) * 4, ccol = lane & 15;
    #pragma unroll
    for (int i = 0; i < 4; i++)
        #pragma unroll
        for (int jn = 0; jn < 4; jn++)
            #pragma unroll
            for (int rg = 0; rg < 4; rg++) {
                int rG = mt * 128 + wr * 64 + i * 16 + crow + rg;
                int nG = nt * 128 + wc * 64 + jn * 16 + ccol;
                size_t idx = (size_t)rG * DIM + nG;
                float d = acc[i][jn][rg] * 0.5f;
                d = fminf(fmaxf(d, -2.0f), 2.0f);
                out[idx] = h[idx] + d;
            }
}

extern "C" void kernel_launch(void* const* d_in, const int* in_sizes, int n_in,
                              void* d_out, int out_size, void* d_ws, size_t ws_size,
                              hipStream_t stream) {
    const float* h      = (const float*)d_in[0];
    const int* mask     = (const int*)d_in[1];
    const float* ln_g   = (const float*)d_in[2];
    const float* ln_b   = (const float*)d_in[3];
    const float* W_out  = (const float*)d_in[4];
    const float* W_nm   = (const float*)d_in[5];
    const float* b_nm   = (const float*)d_in[6];
    const float* W_wg   = (const float*)d_in[7];
    const float* b_wg   = (const float*)d_in[8];
    float* out = (float*)d_out;

    char* ws = (char*)d_ws;
    // ---- region 0: Bpart (NOT zeroed — fully overwritten each chunk) ----
    float* Bpart = (float*)(ws);                                   // 112*CC*NS*4 = 3,670,016 B
    // ---- zeroed region: memS + Kvec (snap no longer needs zeroing) ----
    float* memS  = (float*)(ws + 8388608);                         // 1,835,008 B
    float* Kvec  = (float*)(ws + 8388608 + 1835008);               // 2,048 B
    float* snap  = (float*)(ws + 8388608 + 1835008 + 2048);        // 29,360,128 B (not zeroed)
    const size_t Z0 = 8388608;
    const size_t ZBYTES = 1835008 + 2048;                          // 1,837,056
    // ---- non-zeroed ----
    float* fbuf  = (float*)(ws + 8388608 + 31197184);              // 8,388,608
    float* wgbuf = (float*)(ws + 8388608 + 31197184 + 8388608);    // 131,072
    int*   ssbuf = (int*)  (ws + 8388608 + 31197184 + 8388608 + 131072);  // 131,072
    char*  Mreg  = ws + 8388608 + 31197184 + 8388608 + 262144;     // 58,720,256 region
    float* Gd = (float*)(Mreg);                                    // 16,777,216
    float* R  = (float*)(Mreg + 16777216);
    float* Q  = (float*)(Mreg + 16777216 + 131072);
    float* P2 = (float*)(Mreg + 16777216 + 262144);
    __hip_bfloat16* Mbuf = (__hip_bfloat16*)Mreg;
    // bf16 W_out aliases the Bpart region (dead after the chain)
    __hip_bfloat16* Wb = (__hip_bfloat16*)(ws);                    // 1,605,632 B

    hipMemsetAsync(ws + Z0, 0, ZBYTES, stream);
    hipLaunchKernelGGL(k0_dots, dim3(BB * TT / 4), dim3(256), 0, stream,
                       h, W_nm, W_wg, R, Q, P2);
    hipLaunchKernelGGL(kG_gram, dim3(BB * NC * 2), dim3(256), 0, stream, h, Gd);

    hipLaunchKernelGGL(kS_seq, dim3(BB), dim3(256), 0, stream,
                       Bpart, Gd, R, Q, P2, mask, b_nm, b_wg, W_wg,
                       Kvec, fbuf, wgbuf, ssbuf, 0);
    for (int c = 1; c < NC; ++c) {
        hipLaunchKernelGGL(kB_base, dim3(NSLICE, BB), dim3(256), 0, stream,
                           h, wgbuf, ssbuf, memS, snap, Bpart, c);
        hipLaunchKernelGGL(kS_seq, dim3(BB), dim3(256), 0, stream,
                           Bpart, Gd, R, Q, P2, mask, b_nm, b_wg, W_wg,
                           Kvec, fbuf, wgbuf, ssbuf, c);
    }

    hipLaunchKernelGGL(k1_wcvt, dim3(784), dim3(256), 0, stream, W_out, Wb);
    hipLaunchKernelGGL(k2_replay, dim3(BB * NRC * 2), dim3(448), 0, stream,
                       h, fbuf, wgbuf, ssbuf, snap, Mbuf);
    hipLaunchKernelGGL(k3_ln, dim3(BB * TT / 4), dim3(256), 0, stream,
                       Mbuf, ln_g, ln_b);
    hipLaunchKernelGGL(k4_gemm, dim3(7, 256), dim3(256), 0, stream,
                       Mbuf, Wb, h, out);
}